// Round 2
// baseline (974.521 us; speedup 1.0000x reference)
//
#include <hip/hip_runtime.h>
#include <hip/hip_bf16.h>

#define NN 100000
#define NE 1600000
#define NG 1000

typedef unsigned short u16;
typedef unsigned int u32;
typedef u16 u16x8 __attribute__((ext_vector_type(8)));
typedef u16 u16x4 __attribute__((ext_vector_type(4)));
typedef float f32x4 __attribute__((ext_vector_type(4)));

__device__ __forceinline__ float bf2f(u16 u) {
    union { u32 i; float f; } c; c.i = ((u32)u) << 16; return c.f;
}
__device__ __forceinline__ u16 f2bf(float f) {
    __hip_bfloat16 h = __float2bfloat16(f);
    union { __hip_bfloat16 h; u16 u; } c; c.h = h; return c.u;
}

// ---------------- dtype detector: flag=1 if x is bf16, 0 if f32 ----------------
// For a u32 word w of x: bits (14:7) are the LOW u16's bf16-exponent field if x is
// bf16 pairs (band [110,135] for N(0,1) values, ~99.9%), or f32 mantissa bits
// (uniform, ~10% in band) if x is f32.
__global__ __launch_bounds__(256) void detect_kernel(const u32* __restrict__ xr, int* __restrict__ flag) {
    __shared__ int cnt[256];
    int c = 0;
    for (int i = threadIdx.x; i < 4096; i += 256) {
        u32 e = (xr[i] >> 7) & 0xFFu;
        if (e >= 110u && e <= 135u) c++;
    }
    cnt[threadIdx.x] = c;
    __syncthreads();
    for (int o = 128; o > 0; o >>= 1) {
        if (threadIdx.x < o) cnt[threadIdx.x] += cnt[threadIdx.x + o];
        __syncthreads();
    }
    if (threadIdx.x == 0) flag[0] = (cnt[0] > 2048) ? 1 : 0;
}

// ---------------- canonicalize x -> bf16 (8 elems / thread) ----------------
__global__ __launch_bounds__(256) void cvt_x_kernel(const void* __restrict__ xr, u16* __restrict__ xb,
                                                    const int* __restrict__ flag) {
    int c = blockIdx.x * 256 + threadIdx.x;           // chunk of 8 elements
    const int NC = NN * 128 / 8;                      // 1.6M
    if (c >= NC) return;
    u16x8 o;
    if (flag[0]) {
        o = reinterpret_cast<const u16x8*>(xr)[c];
    } else {
        f32x4 a = reinterpret_cast<const f32x4*>(xr)[c * 2];
        f32x4 b = reinterpret_cast<const f32x4*>(xr)[c * 2 + 1];
        #pragma unroll
        for (int j = 0; j < 4; ++j) { o[j] = f2bf(a[j]); o[4 + j] = f2bf(b[j]); }
    }
    reinterpret_cast<u16x8*>(xb)[c] = o;
}

// ---------------- canonicalize W -> bf16 ----------------
__global__ __launch_bounds__(256) void cvt_w_kernel(const void* __restrict__ wr, u16* __restrict__ wb,
                                                    int nelem, const int* __restrict__ flag) {
    int c = blockIdx.x * 256 + threadIdx.x;
    if (c >= nelem / 8) return;
    u16x8 o;
    if (flag[0]) {
        o = reinterpret_cast<const u16x8*>(wr)[c];
    } else {
        f32x4 a = reinterpret_cast<const f32x4*>(wr)[c * 2];
        f32x4 b = reinterpret_cast<const f32x4*>(wr)[c * 2 + 1];
        #pragma unroll
        for (int j = 0; j < 4; ++j) { o[j] = f2bf(a[j]); o[4 + j] = f2bf(b[j]); }
    }
    reinterpret_cast<u16x8*>(wb)[c] = o;
}

// ---------------- canonicalize bias -> f32 ----------------
__global__ __launch_bounds__(256) void cvt_b_kernel(const void* __restrict__ br, float* __restrict__ bf,
                                                    int nelem, const int* __restrict__ flag) {
    int i = threadIdx.x;
    if (i >= nelem) return;
    bf[i] = flag[0] ? bf2f(reinterpret_cast<const u16*>(br)[i])
                    : reinterpret_cast<const float*>(br)[i];
}

// ---------------- degree histogram ----------------
__global__ __launch_bounds__(256) void hist_kernel(const int* __restrict__ ei, int* __restrict__ counts) {
    int e = blockIdx.x * 256 + threadIdx.x;
    if (e < NE) atomicAdd(&counts[ei[NE + e]], 1);
}

// ---------------- dis = rsqrt(deg+1) ----------------
__global__ __launch_bounds__(256) void dis_kernel(const int* __restrict__ counts, float* __restrict__ dis) {
    int n = blockIdx.x * 256 + threadIdx.x;
    if (n < NN) dis[n] = rsqrtf((float)counts[n] + 1.0f);
}

// ---------------- scan (2048 items / block) ----------------
__global__ __launch_bounds__(256) void scan1_kernel(const int* __restrict__ counts, int* __restrict__ offs,
                                                    int* __restrict__ bsums) {
    __shared__ int sums[256];
    int tid = threadIdx.x;
    int base = blockIdx.x * 2048 + tid * 8;
    int local[8];
    int s = 0;
    #pragma unroll
    for (int i = 0; i < 8; ++i) {
        int v = (base + i < NN) ? counts[base + i] : 0;
        local[i] = s; s += v;
    }
    sums[tid] = s;
    __syncthreads();
    for (int o = 1; o < 256; o <<= 1) {
        int v = (tid >= o) ? sums[tid - o] : 0;
        __syncthreads();
        sums[tid] += v;
        __syncthreads();
    }
    int excl = sums[tid] - s;
    #pragma unroll
    for (int i = 0; i < 8; ++i)
        if (base + i < NN) offs[base + i] = excl + local[i];
    if (tid == 255) bsums[blockIdx.x] = sums[255];
}

__global__ void scan2_kernel(int* __restrict__ bsums, int nb) {
    if (threadIdx.x == 0 && blockIdx.x == 0) {
        int run = 0;
        for (int b = 0; b < nb; ++b) { int t = bsums[b]; bsums[b] = run; run += t; }
    }
}

__global__ __launch_bounds__(256) void scan3_kernel(int* __restrict__ offs, const int* __restrict__ bsums) {
    int i = blockIdx.x * 256 + threadIdx.x;
    if (i < NN) offs[i] += bsums[i >> 11];
}

// ---------------- scatter edges into CSR-by-dst ----------------
__global__ __launch_bounds__(256) void scatter_kernel(const int* __restrict__ ei, const int* __restrict__ offs,
                                                      int* __restrict__ cursor, const float* __restrict__ dis,
                                                      int* __restrict__ srcs, float* __restrict__ norms) {
    int e = blockIdx.x * 256 + threadIdx.x;
    if (e < NE) {
        int s = ei[e], d = ei[NE + e];
        int pos = offs[d] + atomicAdd(&cursor[d], 1);
        srcs[pos] = s;
        norms[pos] = dis[s] * dis[d];
    }
}

// ---------------- GEMM: Hout[N,M](bf16) = Hin[N,128](bf16) @ W[128,M](bf16) (+bias f32) --------
template <int M>
__global__ __launch_bounds__(256) void gemm_kernel(const u16* __restrict__ Hin, const u16* __restrict__ W,
                                                   const float* __restrict__ bias, u16* __restrict__ Hout) {
    constexpr int CT = M / 4;        // col threads (4 cols each)
    constexpr int RT = 256 / CT;     // row threads (8 rows each)
    constexpr int ROWS = RT * 8;     // rows per block
    __shared__ u16 sH[128 * ROWS];   // transposed: [k][row]
    __shared__ u16 sW[128 * M];      // [k][col]
    int tid = threadIdx.x;
    int r0 = blockIdx.x * ROWS;

    for (int c = tid; c < 128 * M / 8; c += 256)
        reinterpret_cast<u16x8*>(sW)[c] = reinterpret_cast<const u16x8*>(W)[c];

    for (int c = tid; c < ROWS * 16; c += 256) {
        int r = c >> 4;
        int kc = (c & 15) << 3;
        int gr = r0 + r;
        u16x8 v = {0, 0, 0, 0, 0, 0, 0, 0};
        if (gr < NN)
            v = reinterpret_cast<const u16x8*>(Hin + (size_t)gr * 128)[c & 15];
        #pragma unroll
        for (int j = 0; j < 8; ++j) sH[(kc + j) * ROWS + r] = v[j];
    }
    __syncthreads();

    int ct = tid % CT, rt = tid / CT;
    float acc[8][4];
    #pragma unroll
    for (int i = 0; i < 8; ++i)
        #pragma unroll
        for (int j = 0; j < 4; ++j) acc[i][j] = 0.0f;

    const u16* hp = sH + rt * 8;
    const u16* wp = sW + ct * 4;
    for (int k = 0; k < 128; ++k) {
        u16x8 hv = *reinterpret_cast<const u16x8*>(hp + k * ROWS);
        u16x4 wv = *reinterpret_cast<const u16x4*>(wp + k * M);
        float wf[4];
        #pragma unroll
        for (int j = 0; j < 4; ++j) wf[j] = bf2f(wv[j]);
        #pragma unroll
        for (int i = 0; i < 8; ++i) {
            float hf = bf2f(hv[i]);
            #pragma unroll
            for (int j = 0; j < 4; ++j) acc[i][j] += hf * wf[j];
        }
    }

    float bf[4] = {0.f, 0.f, 0.f, 0.f};
    if (bias) {
        #pragma unroll
        for (int j = 0; j < 4; ++j) bf[j] = bias[ct * 4 + j];
    }
    #pragma unroll
    for (int i = 0; i < 8; ++i) {
        int gr = r0 + rt * 8 + i;
        if (gr >= NN) break;
        u16x4 o;
        #pragma unroll
        for (int j = 0; j < 4; ++j) o[j] = f2bf(acc[i][j] + bf[j]);
        *reinterpret_cast<u16x4*>(Hout + (size_t)gr * M + ct * 4) = o;
    }
}

// ---------------- conv aggregation: out[n] = sum_e t[src]*norm + t[n]*dis[n]^2 + b ----------------
template <int M, bool RELU>
__global__ __launch_bounds__(256) void agg_kernel(const u16* __restrict__ T, const int* __restrict__ offs,
                                                  const int* __restrict__ counts, const float* __restrict__ dis,
                                                  const int* __restrict__ srcs, const float* __restrict__ norms,
                                                  const float* __restrict__ bias, u16* __restrict__ Hout) {
    constexpr int TPN = M / 2;            // threads per node, 2 feats each
    constexpr int NPB = 256 / TPN;        // nodes per block
    int fp = threadIdx.x % TPN;           // feature pair index
    int n = blockIdx.x * NPB + threadIdx.x / TPN;
    if (n >= NN) return;
    const u32* Tu = reinterpret_cast<const u32*>(T);
    float di = dis[n];
    float sn = di * di;
    u32 tself = Tu[(size_t)n * TPN + fp];
    float a0 = bf2f((u16)(tself & 0xffffu)) * sn + bias[2 * fp];
    float a1 = bf2f((u16)(tself >> 16)) * sn + bias[2 * fp + 1];
    int st = offs[n], cnt = counts[n];
    for (int j = 0; j < cnt; ++j) {
        int s = srcs[st + j];
        float nm = norms[st + j];
        u32 tv = Tu[(size_t)s * TPN + fp];
        a0 += bf2f((u16)(tv & 0xffffu)) * nm;
        a1 += bf2f((u16)(tv >> 16)) * nm;
    }
    if (RELU) { a0 = fmaxf(a0, 0.0f); a1 = fmaxf(a1, 0.0f); }
    u32 ov = (u32)f2bf(a0) | ((u32)f2bf(a1) << 16);
    reinterpret_cast<u32*>(Hout)[(size_t)n * TPN + fp] = ov;
}

// ---------------- global add pool per graph; output dtype branched on flag ----------------
__global__ __launch_bounds__(64) void pool_kernel(const u16* __restrict__ H, const int* __restrict__ batch,
                                                  void* __restrict__ out, const int* __restrict__ flag) {
    int g = blockIdx.x;
    int f = threadIdx.x;
    int lo = 0, hi = NN;
    while (lo < hi) { int mid = (lo + hi) >> 1; if (batch[mid] < g) lo = mid + 1; else hi = mid; }
    int lo2 = lo, hi2 = NN;
    while (lo2 < hi2) { int mid = (lo2 + hi2) >> 1; if (batch[mid] < g + 1) lo2 = mid + 1; else hi2 = mid; }
    float acc = 0.0f;
    for (int n = lo; n < lo2; ++n) acc += bf2f(H[(size_t)n * 64 + f]);
    if (flag[0]) reinterpret_cast<u16*>(out)[g * 64 + f] = f2bf(acc);
    else         reinterpret_cast<float*>(out)[g * 64 + f] = acc;
}

extern "C" void kernel_launch(void* const* d_in, const int* in_sizes, int n_in,
                              void* d_out, int out_size, void* d_ws, size_t ws_size,
                              hipStream_t stream) {
    const void* x     = d_in[0];
    const int* ei     = (const int*)d_in[1];
    const int* batch  = (const int*)d_in[2];
    const void* W_emb = d_in[3];
    const void* b_emb = d_in[4];
    const void* W1    = d_in[5];
    const void* b1    = d_in[6];
    const void* W2    = d_in[7];
    const void* b2    = d_in[8];
    const void* W3    = d_in[9];
    const void* b3    = d_in[10];

    char* p = (char*)d_ws;
    auto alloc = [&](size_t bytes) { void* r = p; p += (bytes + 255) & ~(size_t)255; return r; };
    int*   flag   = (int*)alloc(256);
    int*   counts = (int*)alloc(NN * 4);
    int*   cursor = (int*)alloc(NN * 4);
    int*   offs   = (int*)alloc(NN * 4);
    float* dis    = (float*)alloc(NN * 4);
    int*   bsums  = (int*)alloc(256 * 4);
    int*   srcs   = (int*)alloc((size_t)NE * 4);
    float* norms  = (float*)alloc((size_t)NE * 4);
    u16*   wembB  = (u16*)alloc(128 * 128 * 2);
    u16*   w1B    = (u16*)alloc(128 * 128 * 2);
    u16*   w2B    = (u16*)alloc(128 * 128 * 2);
    u16*   w3B    = (u16*)alloc(128 * 64 * 2);
    float* bembF  = (float*)alloc(128 * 4);
    float* b1F    = (float*)alloc(128 * 4);
    float* b2F    = (float*)alloc(128 * 4);
    float* b3F    = (float*)alloc(64 * 4);
    u16*   hA     = (u16*)alloc((size_t)NN * 128 * 2);
    u16*   hB     = (u16*)alloc((size_t)NN * 128 * 2);   // also holds canonical bf16 x

    hipMemsetAsync(counts, 0, NN * 4, stream);
    hipMemsetAsync(cursor, 0, NN * 4, stream);

    const int EB = (NE + 255) / 256;
    const int NB = (NN + 255) / 256;
    const int SB = (NN + 2047) / 2048;
    const int XC = (NN * 128 / 8 + 255) / 256;   // cvt_x blocks

    detect_kernel<<<1, 256, 0, stream>>>((const u32*)x, flag);
    cvt_x_kernel<<<XC, 256, 0, stream>>>(x, hB, flag);
    cvt_w_kernel<<<(16384 / 8 + 255) / 256, 256, 0, stream>>>(W_emb, wembB, 16384, flag);
    cvt_w_kernel<<<(16384 / 8 + 255) / 256, 256, 0, stream>>>(W1, w1B, 16384, flag);
    cvt_w_kernel<<<(16384 / 8 + 255) / 256, 256, 0, stream>>>(W2, w2B, 16384, flag);
    cvt_w_kernel<<<(8192 / 8 + 255) / 256, 256, 0, stream>>>(W3, w3B, 8192, flag);
    cvt_b_kernel<<<1, 256, 0, stream>>>(b_emb, bembF, 128, flag);
    cvt_b_kernel<<<1, 256, 0, stream>>>(b1, b1F, 128, flag);
    cvt_b_kernel<<<1, 256, 0, stream>>>(b2, b2F, 128, flag);
    cvt_b_kernel<<<1, 256, 0, stream>>>(b3, b3F, 64, flag);

    hist_kernel<<<EB, 256, 0, stream>>>(ei, counts);
    dis_kernel<<<NB, 256, 0, stream>>>(counts, dis);
    scan1_kernel<<<SB, 256, 0, stream>>>(counts, offs, bsums);
    scan2_kernel<<<1, 64, 0, stream>>>(bsums, SB);
    scan3_kernel<<<NB, 256, 0, stream>>>(offs, bsums);
    scatter_kernel<<<EB, 256, 0, stream>>>(ei, offs, cursor, dis, srcs, norms);

    // h0 = x @ W_emb + b_emb  (reads canonical x in hB, writes hA)
    gemm_kernel<128><<<(NN + 63) / 64, 256, 0, stream>>>(hB, wembB, bembF, hA);
    // layer 1
    gemm_kernel<128><<<(NN + 63) / 64, 256, 0, stream>>>(hA, w1B, nullptr, hB);
    agg_kernel<128, true><<<(NN + 3) / 4, 256, 0, stream>>>(hB, offs, counts, dis, srcs, norms, b1F, hA);
    // layer 2
    gemm_kernel<128><<<(NN + 63) / 64, 256, 0, stream>>>(hA, w2B, nullptr, hB);
    agg_kernel<128, true><<<(NN + 3) / 4, 256, 0, stream>>>(hB, offs, counts, dis, srcs, norms, b2F, hA);
    // layer 3 (no relu)
    gemm_kernel<64><<<(NN + 127) / 128, 256, 0, stream>>>(hA, w3B, nullptr, hB);
    agg_kernel<64, false><<<(NN + 7) / 8, 256, 0, stream>>>(hB, offs, counts, dis, srcs, norms, b3F, hA);
    // pool
    pool_kernel<<<NG, 64, 0, stream>>>(hA, batch, d_out, flag);
}

// Round 3
// 553.672 us; speedup vs baseline: 1.7601x; 1.7601x over previous
//
#include <hip/hip_runtime.h>
#include <hip/hip_bf16.h>

#define NN 100000
#define NE 1600000
#define NG 1000

typedef unsigned short u16;
typedef unsigned int u32;
typedef u16 u16x8 __attribute__((ext_vector_type(8)));
typedef u16 u16x4 __attribute__((ext_vector_type(4)));
typedef u32 u32x4 __attribute__((ext_vector_type(4)));
typedef float f32x4 __attribute__((ext_vector_type(4)));
typedef __attribute__((ext_vector_type(8))) short s16x8;
typedef __attribute__((ext_vector_type(4))) float facc4;

__device__ __forceinline__ float bf2f(u16 u) {
    union { u32 i; float f; } c; c.i = ((u32)u) << 16; return c.f;
}
__device__ __forceinline__ u16 f2bf(float f) {
    __hip_bfloat16 h = __float2bfloat16(f);
    union { __hip_bfloat16 h; u16 u; } c; c.h = h; return c.u;
}

// ---------------- dtype detector: flag=1 if x is bf16, 0 if f32 ----------------
__global__ __launch_bounds__(256) void detect_kernel(const u32* __restrict__ xr, int* __restrict__ flag) {
    __shared__ int cnt[256];
    int c = 0;
    for (int i = threadIdx.x; i < 4096; i += 256) {
        u32 e = (xr[i] >> 7) & 0xFFu;
        if (e >= 110u && e <= 135u) c++;
    }
    cnt[threadIdx.x] = c;
    __syncthreads();
    for (int o = 128; o > 0; o >>= 1) {
        if (threadIdx.x < o) cnt[threadIdx.x] += cnt[threadIdx.x + o];
        __syncthreads();
    }
    if (threadIdx.x == 0) flag[0] = (cnt[0] > 2048) ? 1 : 0;
}

// ---------------- canonicalize x -> bf16 ----------------
__global__ __launch_bounds__(256) void cvt_x_kernel(const void* __restrict__ xr, u16* __restrict__ xb,
                                                    const int* __restrict__ flag) {
    int c = blockIdx.x * 256 + threadIdx.x;
    const int NC = NN * 128 / 8;
    if (c >= NC) return;
    u16x8 o;
    if (flag[0]) {
        o = reinterpret_cast<const u16x8*>(xr)[c];
    } else {
        f32x4 a = reinterpret_cast<const f32x4*>(xr)[c * 2];
        f32x4 b = reinterpret_cast<const f32x4*>(xr)[c * 2 + 1];
        #pragma unroll
        for (int j = 0; j < 4; ++j) { o[j] = f2bf(a[j]); o[4 + j] = f2bf(b[j]); }
    }
    reinterpret_cast<u16x8*>(xb)[c] = o;
}

// ---------------- canonicalize + transpose W[k][n] -> Wt[n][k] (bf16) ----------------
__global__ __launch_bounds__(256) void cvt_wt_kernel(const void* __restrict__ wr, u16* __restrict__ wt,
                                                     int Mcols, const int* __restrict__ flag) {
    int o = blockIdx.x * 256 + threadIdx.x;     // o indexes Wt: n = o>>7, k = o&127
    if (o >= Mcols * 128) return;
    int n = o >> 7, k = o & 127;
    u16 v;
    if (flag[0]) v = reinterpret_cast<const u16*>(wr)[k * Mcols + n];
    else         v = f2bf(reinterpret_cast<const float*>(wr)[k * Mcols + n]);
    wt[o] = v;
}

// ---------------- canonicalize bias -> f32 ----------------
__global__ __launch_bounds__(256) void cvt_b_kernel(const void* __restrict__ br, float* __restrict__ bf,
                                                    int nelem, const int* __restrict__ flag) {
    int i = threadIdx.x;
    if (i >= nelem) return;
    bf[i] = flag[0] ? bf2f(reinterpret_cast<const u16*>(br)[i])
                    : reinterpret_cast<const float*>(br)[i];
}

// ---------------- degree histogram ----------------
__global__ __launch_bounds__(256) void hist_kernel(const int* __restrict__ ei, int* __restrict__ counts) {
    int e = blockIdx.x * 256 + threadIdx.x;
    if (e < NE) atomicAdd(&counts[ei[NE + e]], 1);
}

// ---------------- dis = rsqrt(deg+1) ----------------
__global__ __launch_bounds__(256) void dis_kernel(const int* __restrict__ counts, float* __restrict__ dis) {
    int n = blockIdx.x * 256 + threadIdx.x;
    if (n < NN) dis[n] = rsqrtf((float)counts[n] + 1.0f);
}

// ---------------- scan (2048 items / block) ----------------
__global__ __launch_bounds__(256) void scan1_kernel(const int* __restrict__ counts, int* __restrict__ offs,
                                                    int* __restrict__ bsums) {
    __shared__ int sums[256];
    int tid = threadIdx.x;
    int base = blockIdx.x * 2048 + tid * 8;
    int local[8];
    int s = 0;
    #pragma unroll
    for (int i = 0; i < 8; ++i) {
        int v = (base + i < NN) ? counts[base + i] : 0;
        local[i] = s; s += v;
    }
    sums[tid] = s;
    __syncthreads();
    for (int o = 1; o < 256; o <<= 1) {
        int v = (tid >= o) ? sums[tid - o] : 0;
        __syncthreads();
        sums[tid] += v;
        __syncthreads();
    }
    int excl = sums[tid] - s;
    #pragma unroll
    for (int i = 0; i < 8; ++i)
        if (base + i < NN) offs[base + i] = excl + local[i];
    if (tid == 255) bsums[blockIdx.x] = sums[255];
}

__global__ void scan2_kernel(int* __restrict__ bsums, int nb) {
    if (threadIdx.x == 0 && blockIdx.x == 0) {
        int run = 0;
        for (int b = 0; b < nb; ++b) { int t = bsums[b]; bsums[b] = run; run += t; }
    }
}

__global__ __launch_bounds__(256) void scan3_kernel(int* __restrict__ offs, const int* __restrict__ bsums) {
    int i = blockIdx.x * 256 + threadIdx.x;
    if (i < NN) offs[i] += bsums[i >> 11];
}

// ---------------- scatter edges into CSR-by-dst, packed (src, norm) ----------------
__global__ __launch_bounds__(256) void scatter_kernel(const int* __restrict__ ei, const int* __restrict__ offs,
                                                      int* __restrict__ cursor, const float* __restrict__ dis,
                                                      int2* __restrict__ edges) {
    int e = blockIdx.x * 256 + threadIdx.x;
    if (e < NE) {
        int s = ei[e], d = ei[NE + e];
        int pos = offs[d] + atomicAdd(&cursor[d], 1);
        int2 pk;
        pk.x = s;
        pk.y = __float_as_int(dis[s] * dis[d]);
        edges[pos] = pk;
    }
}

// ---------------- MFMA GEMM: Hout[N,M](bf16) = Hin[N,128] @ W[128,M], Wt given as [n][k] ------
// Block: 256 thr = 4 waves, 64 rows. Wave: 16 rows x M cols via 16x16x32 bf16 MFMA.
// Layouts (verified m89/m120): A[m=lane&15][k=quad*8+j]; B[n=lane&15][k=quad*8+j];
// D: col=lane&15, row=quad*4+reg.
template <int M>
__global__ __launch_bounds__(256) void gemm_mfma(const u16* __restrict__ Hin, const u16* __restrict__ Wt,
                                                 const float* __restrict__ bias, u16* __restrict__ Hout) {
    constexpr int LDW = 136;                 // LDS row stride (u16): 272 B -> 2-way bank alias (free)
    __shared__ u16 sW[M * LDW];
    int tid = threadIdx.x;
    // stage Wt[n][k] -> sW[n*LDW + k], coalesced dwordx4
    for (int c = tid; c < M * 16; c += 256) {
        int n = c >> 4, kc = (c & 15) << 3;
        *reinterpret_cast<u16x8*>(sW + n * LDW + kc) = reinterpret_cast<const u16x8*>(Wt)[c];
    }
    __syncthreads();

    int wv = tid >> 6, lane = tid & 63;
    int m = lane & 15, quad = lane >> 4;
    int r0 = blockIdx.x * 64 + wv * 16;
    constexpr int NT = M / 16;
    facc4 acc[NT];
    #pragma unroll
    for (int t = 0; t < NT; ++t) acc[t] = (facc4){0.f, 0.f, 0.f, 0.f};

    const u16* arow = Hin + (size_t)(r0 + m) * 128 + quad * 8;
    #pragma unroll
    for (int k0 = 0; k0 < 128; k0 += 32) {
        s16x8 a = *reinterpret_cast<const s16x8*>(arow + k0);
        #pragma unroll
        for (int t = 0; t < NT; ++t) {
            s16x8 b = *reinterpret_cast<const s16x8*>(sW + (t * 16 + m) * LDW + k0 + quad * 8);
            acc[t] = __builtin_amdgcn_mfma_f32_16x16x32_bf16(a, b, acc[t], 0, 0, 0);
        }
    }

    #pragma unroll
    for (int t = 0; t < NT; ++t) {
        int col = t * 16 + m;
        float bv = bias ? bias[col] : 0.0f;
        #pragma unroll
        for (int r = 0; r < 4; ++r) {
            int orow = r0 + quad * 4 + r;
            if (orow < NN)
                Hout[(size_t)orow * M + col] = f2bf(acc[t][r] + bv);
        }
    }
}

// ---------------- conv aggregation: out[n] = sum_e t[src]*norm + t[n]/deg + b ----------------
// TPN = M/8 lanes per node, dwordx4 (8 bf16) per lane, 4-deep gather pipeline.
template <int M, bool RELU>
__global__ __launch_bounds__(256) void agg_kernel(const u16* __restrict__ T, const int* __restrict__ offs,
                                                  const int* __restrict__ counts, const float* __restrict__ dis,
                                                  const int2* __restrict__ edges,
                                                  const float* __restrict__ bias, u16* __restrict__ Hout) {
    constexpr int TPN = M / 8;            // threads per node (8 feats / 16 B each)
    constexpr int NPB = 256 / TPN;        // nodes per block
    int lane = threadIdx.x % TPN;
    int n = blockIdx.x * NPB + threadIdx.x / TPN;
    if (n >= NN) return;
    const u32x4* T4 = reinterpret_cast<const u32x4*>(T);

    float di = dis[n];
    float sn = di * di;
    u32x4 ts = T4[(size_t)n * TPN + lane];
    float acc[8];
    #pragma unroll
    for (int q = 0; q < 4; ++q) {
        acc[2 * q]     = bf2f((u16)(ts[q] & 0xffffu)) * sn + bias[lane * 8 + 2 * q];
        acc[2 * q + 1] = bf2f((u16)(ts[q] >> 16))     * sn + bias[lane * 8 + 2 * q + 1];
    }

    int st = offs[n], cnt = counts[n];
    int j = 0;
    for (; j + 4 <= cnt; j += 4) {
        int2 e0 = edges[st + j];
        int2 e1 = edges[st + j + 1];
        int2 e2 = edges[st + j + 2];
        int2 e3 = edges[st + j + 3];
        u32x4 g0 = T4[(size_t)e0.x * TPN + lane];
        u32x4 g1 = T4[(size_t)e1.x * TPN + lane];
        u32x4 g2 = T4[(size_t)e2.x * TPN + lane];
        u32x4 g3 = T4[(size_t)e3.x * TPN + lane];
        float w0 = __int_as_float(e0.y), w1 = __int_as_float(e1.y);
        float w2 = __int_as_float(e2.y), w3 = __int_as_float(e3.y);
        #pragma unroll
        for (int q = 0; q < 4; ++q) {
            acc[2 * q]     += bf2f((u16)(g0[q] & 0xffffu)) * w0;
            acc[2 * q + 1] += bf2f((u16)(g0[q] >> 16))     * w0;
            acc[2 * q]     += bf2f((u16)(g1[q] & 0xffffu)) * w1;
            acc[2 * q + 1] += bf2f((u16)(g1[q] >> 16))     * w1;
            acc[2 * q]     += bf2f((u16)(g2[q] & 0xffffu)) * w2;
            acc[2 * q + 1] += bf2f((u16)(g2[q] >> 16))     * w2;
            acc[2 * q]     += bf2f((u16)(g3[q] & 0xffffu)) * w3;
            acc[2 * q + 1] += bf2f((u16)(g3[q] >> 16))     * w3;
        }
    }
    for (; j < cnt; ++j) {
        int2 e = edges[st + j];
        u32x4 g = T4[(size_t)e.x * TPN + lane];
        float w = __int_as_float(e.y);
        #pragma unroll
        for (int q = 0; q < 4; ++q) {
            acc[2 * q]     += bf2f((u16)(g[q] & 0xffffu)) * w;
            acc[2 * q + 1] += bf2f((u16)(g[q] >> 16))     * w;
        }
    }

    u32x4 ov;
    #pragma unroll
    for (int q = 0; q < 4; ++q) {
        float a0 = acc[2 * q], a1 = acc[2 * q + 1];
        if (RELU) { a0 = fmaxf(a0, 0.0f); a1 = fmaxf(a1, 0.0f); }
        ov[q] = (u32)f2bf(a0) | ((u32)f2bf(a1) << 16);
    }
    reinterpret_cast<u32x4*>(Hout)[(size_t)n * TPN + lane] = ov;
}

// ---------------- global add pool per graph; output dtype branched on flag ----------------
__global__ __launch_bounds__(64) void pool_kernel(const u16* __restrict__ H, const int* __restrict__ batch,
                                                  void* __restrict__ out, const int* __restrict__ flag) {
    int g = blockIdx.x;
    int f = threadIdx.x;
    int lo = 0, hi = NN;
    while (lo < hi) { int mid = (lo + hi) >> 1; if (batch[mid] < g) lo = mid + 1; else hi = mid; }
    int lo2 = lo, hi2 = NN;
    while (lo2 < hi2) { int mid = (lo2 + hi2) >> 1; if (batch[mid] < g + 1) lo2 = mid + 1; else hi2 = mid; }
    float acc = 0.0f;
    for (int n = lo; n < lo2; ++n) acc += bf2f(H[(size_t)n * 64 + f]);
    if (flag[0]) reinterpret_cast<u16*>(out)[g * 64 + f] = f2bf(acc);
    else         reinterpret_cast<float*>(out)[g * 64 + f] = acc;
}

extern "C" void kernel_launch(void* const* d_in, const int* in_sizes, int n_in,
                              void* d_out, int out_size, void* d_ws, size_t ws_size,
                              hipStream_t stream) {
    const void* x     = d_in[0];
    const int* ei     = (const int*)d_in[1];
    const int* batch  = (const int*)d_in[2];
    const void* W_emb = d_in[3];
    const void* b_emb = d_in[4];
    const void* W1    = d_in[5];
    const void* b1    = d_in[6];
    const void* W2    = d_in[7];
    const void* b2    = d_in[8];
    const void* W3    = d_in[9];
    const void* b3    = d_in[10];

    char* p = (char*)d_ws;
    auto alloc = [&](size_t bytes) { void* r = p; p += (bytes + 255) & ~(size_t)255; return r; };
    int*   flag   = (int*)alloc(256);
    int*   counts = (int*)alloc(NN * 4);
    int*   cursor = (int*)alloc(NN * 4);
    int*   offs   = (int*)alloc(NN * 4);
    float* dis    = (float*)alloc(NN * 4);
    int*   bsums  = (int*)alloc(256 * 4);
    int2*  edges  = (int2*)alloc((size_t)NE * 8);
    u16*   wembT  = (u16*)alloc(128 * 128 * 2);
    u16*   w1T    = (u16*)alloc(128 * 128 * 2);
    u16*   w2T    = (u16*)alloc(128 * 128 * 2);
    u16*   w3T    = (u16*)alloc(64 * 128 * 2);
    float* bembF  = (float*)alloc(128 * 4);
    float* b1F    = (float*)alloc(128 * 4);
    float* b2F    = (float*)alloc(128 * 4);
    float* b3F    = (float*)alloc(64 * 4);
    u16*   hA     = (u16*)alloc((size_t)(NN + 64) * 128 * 2);   // +64 rows MFMA overread pad
    u16*   hB     = (u16*)alloc((size_t)(NN + 64) * 128 * 2);   // also holds canonical bf16 x

    hipMemsetAsync(counts, 0, NN * 4, stream);
    hipMemsetAsync(cursor, 0, NN * 4, stream);

    const int EB = (NE + 255) / 256;
    const int NB = (NN + 255) / 256;
    const int SB = (NN + 2047) / 2048;
    const int XC = (NN * 128 / 8 + 255) / 256;
    const int GB = (NN + 63) / 64;          // 1563 blocks of 64 rows

    detect_kernel<<<1, 256, 0, stream>>>((const u32*)x, flag);
    cvt_x_kernel<<<XC, 256, 0, stream>>>(x, hB, flag);
    cvt_wt_kernel<<<64, 256, 0, stream>>>(W_emb, wembT, 128, flag);
    cvt_wt_kernel<<<64, 256, 0, stream>>>(W1, w1T, 128, flag);
    cvt_wt_kernel<<<64, 256, 0, stream>>>(W2, w2T, 128, flag);
    cvt_wt_kernel<<<32, 256, 0, stream>>>(W3, w3T, 64, flag);
    cvt_b_kernel<<<1, 256, 0, stream>>>(b_emb, bembF, 128, flag);
    cvt_b_kernel<<<1, 256, 0, stream>>>(b1, b1F, 128, flag);
    cvt_b_kernel<<<1, 256, 0, stream>>>(b2, b2F, 128, flag);
    cvt_b_kernel<<<1, 256, 0, stream>>>(b3, b3F, 64, flag);

    hist_kernel<<<EB, 256, 0, stream>>>(ei, counts);
    dis_kernel<<<NB, 256, 0, stream>>>(counts, dis);
    scan1_kernel<<<SB, 256, 0, stream>>>(counts, offs, bsums);
    scan2_kernel<<<1, 64, 0, stream>>>(bsums, SB);
    scan3_kernel<<<NB, 256, 0, stream>>>(offs, bsums);
    scatter_kernel<<<EB, 256, 0, stream>>>(ei, offs, cursor, dis, edges);

    // h0 = x @ W_emb + b_emb  (reads canonical x in hB, writes hA)
    gemm_mfma<128><<<GB, 256, 0, stream>>>(hB, wembT, bembF, hA);
    // layer 1
    gemm_mfma<128><<<GB, 256, 0, stream>>>(hA, w1T, nullptr, hB);
    agg_kernel<128, true><<<(NN + 15) / 16, 256, 0, stream>>>(hB, offs, counts, dis, edges, b1F, hA);
    // layer 2
    gemm_mfma<128><<<GB, 256, 0, stream>>>(hA, w2T, nullptr, hB);
    agg_kernel<128, true><<<(NN + 15) / 16, 256, 0, stream>>>(hB, offs, counts, dis, edges, b2F, hA);
    // layer 3 (no relu)
    gemm_mfma<64><<<GB, 256, 0, stream>>>(hA, w3T, nullptr, hB);
    agg_kernel<64, false><<<(NN + 31) / 32, 256, 0, stream>>>(hB, offs, counts, dis, edges, b3F, hA);
    // pool
    pool_kernel<<<NG, 64, 0, stream>>>(hA, batch, d_out, flag);
}

// Round 4
// 543.162 us; speedup vs baseline: 1.7942x; 1.0193x over previous
//
#include <hip/hip_runtime.h>
#include <hip/hip_bf16.h>

#define NN 100000
#define NE 1600000
#define NG 1000

typedef unsigned short u16;
typedef unsigned int u32;
typedef u16 u16x8 __attribute__((ext_vector_type(8)));
typedef u32 u32x4 __attribute__((ext_vector_type(4)));
typedef float f32x4 __attribute__((ext_vector_type(4)));
typedef __attribute__((ext_vector_type(8))) short s16x8;
typedef __attribute__((ext_vector_type(4))) float facc4;

__device__ __forceinline__ float bf2f(u16 u) {
    union { u32 i; float f; } c; c.i = ((u32)u) << 16; return c.f;
}
__device__ __forceinline__ u16 f2bf(float f) {
    __hip_bfloat16 h = __float2bfloat16(f);
    union { __hip_bfloat16 h; u16 u; } c; c.h = h; return c.u;
}

// ---------------- dtype detector: flag=1 if x is bf16, 0 if f32 ----------------
__global__ __launch_bounds__(256) void detect_kernel(const u32* __restrict__ xr, int* __restrict__ flag) {
    __shared__ int cnt[256];
    int c = 0;
    for (int i = threadIdx.x; i < 4096; i += 256) {
        u32 e = (xr[i] >> 7) & 0xFFu;
        if (e >= 110u && e <= 135u) c++;
    }
    cnt[threadIdx.x] = c;
    __syncthreads();
    for (int o = 128; o > 0; o >>= 1) {
        if (threadIdx.x < o) cnt[threadIdx.x] += cnt[threadIdx.x + o];
        __syncthreads();
    }
    if (threadIdx.x == 0) flag[0] = (cnt[0] > 2048) ? 1 : 0;
}

// ---------------- MEGA prep: cvt_x | cvt_wt x4 | cvt_b x4 | hist, by block range ----------------
// block ranges: [0,6250) cvt_x ; [6250,6474) cvt_wt ; [6474,6476) cvt_b ; [6476,8039) hist
#define MEGA_NB 8039
__global__ __launch_bounds__(256) void mega_prep(
    const void* __restrict__ x, const int* __restrict__ flag, u16* __restrict__ xb,
    const void* __restrict__ Wemb, const void* __restrict__ W1, const void* __restrict__ W2,
    const void* __restrict__ W3, u16* __restrict__ wembT, u16* __restrict__ w1T,
    u16* __restrict__ w2T, u16* __restrict__ w3T,
    const void* __restrict__ bemb, const void* __restrict__ b1, const void* __restrict__ b2,
    const void* __restrict__ b3, float* __restrict__ bembF, float* __restrict__ b1F,
    float* __restrict__ b2F, float* __restrict__ b3F,
    const int* __restrict__ ei, int* __restrict__ counts)
{
    int b = blockIdx.x, tid = threadIdx.x;
    int fl = flag[0];
    if (b < 6250) {                       // ---- cvt_x (skip when already bf16)
        if (fl) return;
        int c = b * 256 + tid;            // chunk of 8 elems
        f32x4 a = reinterpret_cast<const f32x4*>(x)[c * 2];
        f32x4 d = reinterpret_cast<const f32x4*>(x)[c * 2 + 1];
        u16x8 o;
        #pragma unroll
        for (int j = 0; j < 4; ++j) { o[j] = f2bf(a[j]); o[4 + j] = f2bf(d[j]); }
        reinterpret_cast<u16x8*>(xb)[c] = o;
    } else if (b < 6474) {                // ---- cvt_wt (transpose W[k][m] -> Wt[m][k])
        int o = (b - 6250) * 256 + tid;   // 0..57343
        const void* src; u16* dst; int M; int ol;
        if (o < 16384)      { src = Wemb; dst = wembT; M = 128; ol = o; }
        else if (o < 32768) { src = W1;   dst = w1T;   M = 128; ol = o - 16384; }
        else if (o < 49152) { src = W2;   dst = w2T;   M = 128; ol = o - 32768; }
        else                { src = W3;   dst = w3T;   M = 64;  ol = o - 49152; }
        int n = ol >> 7, k = ol & 127;
        u16 v = fl ? reinterpret_cast<const u16*>(src)[k * M + n]
                   : f2bf(reinterpret_cast<const float*>(src)[k * M + n]);
        dst[ol] = v;
    } else if (b < 6476) {                // ---- cvt_b
        int i = (b - 6474) * 256 + tid;   // 0..447
        if (i >= 448) return;
        const void* src; float* dst; int il;
        if (i < 128)      { src = bemb; dst = bembF; il = i; }
        else if (i < 256) { src = b1;   dst = b1F;   il = i - 128; }
        else if (i < 384) { src = b2;   dst = b2F;   il = i - 256; }
        else              { src = b3;   dst = b3F;   il = i - 384; }
        dst[il] = fl ? bf2f(reinterpret_cast<const u16*>(src)[il])
                     : reinterpret_cast<const float*>(src)[il];
    } else {                              // ---- hist (4 edges / thread)
        int e0 = (b - 6476) * 1024 + tid * 4;
        if (e0 >= NE) return;
        int4 d4 = *reinterpret_cast<const int4*>(ei + NE + e0);
        atomicAdd(&counts[d4.x], 1);
        atomicAdd(&counts[d4.y], 1);
        atomicAdd(&counts[d4.z], 1);
        atomicAdd(&counts[d4.w], 1);
    }
}

// ---------------- scan1 (+ dis, + cursor zero) ----------------
__global__ __launch_bounds__(256) void scan1_kernel(const int* __restrict__ counts, int* __restrict__ offs,
                                                    int* __restrict__ bsums, float* __restrict__ dis,
                                                    int* __restrict__ cursor) {
    __shared__ int sums[256];
    int tid = threadIdx.x;
    int base = blockIdx.x * 2048 + tid * 8;
    int local[8];
    int s = 0;
    #pragma unroll
    for (int i = 0; i < 8; ++i) {
        int v = 0;
        if (base + i < NN) {
            v = counts[base + i];
            dis[base + i] = rsqrtf((float)v + 1.0f);
            cursor[base + i] = 0;
        }
        local[i] = s; s += v;
    }
    sums[tid] = s;
    __syncthreads();
    for (int o = 1; o < 256; o <<= 1) {
        int v = (tid >= o) ? sums[tid - o] : 0;
        __syncthreads();
        sums[tid] += v;
        __syncthreads();
    }
    int excl = sums[tid] - s;
    #pragma unroll
    for (int i = 0; i < 8; ++i)
        if (base + i < NN) offs[base + i] = excl + local[i];
    if (tid == 255) bsums[blockIdx.x] = sums[255];
}

// ---------------- scan3 (folds old scan2: per-block serial prefix of 49 bsums) ----------------
__global__ __launch_bounds__(256) void scan3_kernel(int* __restrict__ offs, const int* __restrict__ bsums) {
    __shared__ int addv;
    int i = blockIdx.x * 256 + threadIdx.x;
    int bucket = blockIdx.x >> 3;         // (b*256)>>11, uniform per block
    if (threadIdx.x == 0) {
        int s = 0;
        for (int k = 0; k < bucket; ++k) s += bsums[k];
        addv = s;
    }
    __syncthreads();
    if (i < NN) offs[i] += addv;
}

// ---------------- scatter: 4 edges/thread, 4-byte entries (src only) ----------------
__global__ __launch_bounds__(256) void scatter_kernel(const int* __restrict__ ei, const int* __restrict__ offs,
                                                      int* __restrict__ cursor, int* __restrict__ srcs) {
    int t = blockIdx.x * 256 + threadIdx.x;
    int e0 = t * 4;
    if (e0 >= NE) return;
    int4 s4 = *reinterpret_cast<const int4*>(ei + e0);
    int4 d4 = *reinterpret_cast<const int4*>(ei + NE + e0);
    int p0 = offs[d4.x] + atomicAdd(&cursor[d4.x], 1);
    int p1 = offs[d4.y] + atomicAdd(&cursor[d4.y], 1);
    int p2 = offs[d4.z] + atomicAdd(&cursor[d4.z], 1);
    int p3 = offs[d4.w] + atomicAdd(&cursor[d4.w], 1);
    srcs[p0] = s4.x;
    srcs[p1] = s4.y;
    srcs[p2] = s4.z;
    srcs[p3] = s4.w;
}

// ---------------- MFMA GEMM: Hout[N,M] = A[N,128] @ W, Wt given as [n][k] ----------------
// A = (HinAlt && flag) ? HinAlt : Hin  (runtime dtype select for the embedding layer)
template <int M>
__global__ __launch_bounds__(256) void gemm_mfma(const u16* __restrict__ Hin, const u16* __restrict__ HinAlt,
                                                 const int* __restrict__ flag, const u16* __restrict__ Wt,
                                                 const float* __restrict__ bias, u16* __restrict__ Hout) {
    constexpr int LDW = 136;
    __shared__ u16 sW[M * LDW];
    int tid = threadIdx.x;
    const u16* A = (HinAlt != nullptr && flag[0]) ? HinAlt : Hin;
    for (int c = tid; c < M * 16; c += 256) {
        int n = c >> 4, kc = (c & 15) << 3;
        *reinterpret_cast<u16x8*>(sW + n * LDW + kc) = reinterpret_cast<const u16x8*>(Wt)[c];
    }
    __syncthreads();

    int wv = tid >> 6, lane = tid & 63;
    int m = lane & 15, quad = lane >> 4;
    int r0 = blockIdx.x * 64 + wv * 16;
    int ar = r0 + m; if (ar >= NN) ar = NN - 1;   // clamp: OOB tile rows only feed OOB outputs
    constexpr int NT = M / 16;
    facc4 acc[NT];
    #pragma unroll
    for (int t = 0; t < NT; ++t) acc[t] = (facc4){0.f, 0.f, 0.f, 0.f};

    const u16* arow = A + (size_t)ar * 128 + quad * 8;
    #pragma unroll
    for (int k0 = 0; k0 < 128; k0 += 32) {
        s16x8 a = *reinterpret_cast<const s16x8*>(arow + k0);
        #pragma unroll
        for (int t = 0; t < NT; ++t) {
            s16x8 bfr = *reinterpret_cast<const s16x8*>(sW + (t * 16 + m) * LDW + k0 + quad * 8);
            acc[t] = __builtin_amdgcn_mfma_f32_16x16x32_bf16(a, bfr, acc[t], 0, 0, 0);
        }
    }

    #pragma unroll
    for (int t = 0; t < NT; ++t) {
        int col = t * 16 + m;
        float bv = bias ? bias[col] : 0.0f;
        #pragma unroll
        for (int r = 0; r < 4; ++r) {
            int orow = r0 + quad * 4 + r;
            if (orow < NN)
                Hout[(size_t)orow * M + col] = f2bf(acc[t][r] + bv);
        }
    }
}

// ---------------- FUSED: agg(128-wide, relu) -> LDS -> MFMA gemm (x W[128,MOUT]) ----------------
template <int MOUT>
__global__ __launch_bounds__(256) void fused_agg_gemm(const u16* __restrict__ T, const int* __restrict__ offs,
                                                      const int* __restrict__ counts, const float* __restrict__ dis,
                                                      const int* __restrict__ srcs, const float* __restrict__ aggbias,
                                                      const u16* __restrict__ Wt, u16* __restrict__ Hout) {
    constexpr int LDW = 136;
    __shared__ u16 sW[MOUT * LDW];
    __shared__ u16 sA[64 * LDW];
    int tid = threadIdx.x;
    // stage W (consumed after the agg-phase barrier)
    for (int c = tid; c < MOUT * 16; c += 256) {
        int n = c >> 4, kc = (c & 15) << 3;
        *reinterpret_cast<u16x8*>(sW + n * LDW + kc) = reinterpret_cast<const u16x8*>(Wt)[c];
    }

    // ---- agg phase: 16 groups x 16 lanes; each group does 4 nodes ----
    int lane = tid & 15, grp = tid >> 4;
    const u32x4* T4 = reinterpret_cast<const u32x4*>(T);
    for (int i = 0; i < 4; ++i) {
        int nl = grp * 4 + i;
        int n = blockIdx.x * 64 + nl;
        bool valid = n < NN;
        int nc = valid ? n : NN - 1;
        float di = dis[nc];
        float sn = di * di;
        u32x4 ts = T4[(size_t)nc * 16 + lane];
        float acc[8];
        #pragma unroll
        for (int q = 0; q < 4; ++q) {
            acc[2 * q]     = bf2f((u16)(ts[q] & 0xffffu)) * sn + aggbias[lane * 8 + 2 * q];
            acc[2 * q + 1] = bf2f((u16)(ts[q] >> 16))     * sn + aggbias[lane * 8 + 2 * q + 1];
        }
        int st = offs[nc], cnt = valid ? counts[nc] : 0;
        int j = 0;
        for (; j + 4 <= cnt; j += 4) {
            int e0 = srcs[st + j], e1 = srcs[st + j + 1], e2 = srcs[st + j + 2], e3 = srcs[st + j + 3];
            float w0 = dis[e0] * di, w1 = dis[e1] * di, w2 = dis[e2] * di, w3 = dis[e3] * di;
            u32x4 g0 = T4[(size_t)e0 * 16 + lane];
            u32x4 g1 = T4[(size_t)e1 * 16 + lane];
            u32x4 g2 = T4[(size_t)e2 * 16 + lane];
            u32x4 g3 = T4[(size_t)e3 * 16 + lane];
            #pragma unroll
            for (int q = 0; q < 4; ++q) {
                acc[2 * q]     += bf2f((u16)(g0[q] & 0xffffu)) * w0;
                acc[2 * q + 1] += bf2f((u16)(g0[q] >> 16))     * w0;
                acc[2 * q]     += bf2f((u16)(g1[q] & 0xffffu)) * w1;
                acc[2 * q + 1] += bf2f((u16)(g1[q] >> 16))     * w1;
                acc[2 * q]     += bf2f((u16)(g2[q] & 0xffffu)) * w2;
                acc[2 * q + 1] += bf2f((u16)(g2[q] >> 16))     * w2;
                acc[2 * q]     += bf2f((u16)(g3[q] & 0xffffu)) * w3;
                acc[2 * q + 1] += bf2f((u16)(g3[q] >> 16))     * w3;
            }
        }
        for (; j < cnt; ++j) {
            int e = srcs[st + j];
            float w = dis[e] * di;
            u32x4 g = T4[(size_t)e * 16 + lane];
            #pragma unroll
            for (int q = 0; q < 4; ++q) {
                acc[2 * q]     += bf2f((u16)(g[q] & 0xffffu)) * w;
                acc[2 * q + 1] += bf2f((u16)(g[q] >> 16))     * w;
            }
        }
        u16x8 pk;
        #pragma unroll
        for (int q = 0; q < 4; ++q) {
            pk[2 * q]     = f2bf(fmaxf(acc[2 * q], 0.0f));
            pk[2 * q + 1] = f2bf(fmaxf(acc[2 * q + 1], 0.0f));
        }
        *reinterpret_cast<u16x8*>(sA + nl * LDW + lane * 8) = pk;
    }
    __syncthreads();

    // ---- gemm phase: 4 waves x 16 rows ----
    int wv = tid >> 6, l64 = tid & 63;
    int m = l64 & 15, quad = l64 >> 4;
    int r0 = blockIdx.x * 64 + wv * 16;
    constexpr int NT = MOUT / 16;
    facc4 gacc[NT];
    #pragma unroll
    for (int t = 0; t < NT; ++t) gacc[t] = (facc4){0.f, 0.f, 0.f, 0.f};
    #pragma unroll
    for (int k0 = 0; k0 < 128; k0 += 32) {
        s16x8 a = *reinterpret_cast<const s16x8*>(sA + (wv * 16 + m) * LDW + k0 + quad * 8);
        #pragma unroll
        for (int t = 0; t < NT; ++t) {
            s16x8 bfr = *reinterpret_cast<const s16x8*>(sW + (t * 16 + m) * LDW + k0 + quad * 8);
            gacc[t] = __builtin_amdgcn_mfma_f32_16x16x32_bf16(a, bfr, gacc[t], 0, 0, 0);
        }
    }
    #pragma unroll
    for (int t = 0; t < NT; ++t) {
        int col = t * 16 + m;
        #pragma unroll
        for (int r = 0; r < 4; ++r) {
            int orow = r0 + quad * 4 + r;
            if (orow < NN)
                Hout[(size_t)orow * MOUT + col] = f2bf(gacc[t][r]);
        }
    }
}

// ---------------- standalone agg (layer 3, 64-wide, no relu) ----------------
template <int M, bool RELU>
__global__ __launch_bounds__(256) void agg_kernel(const u16* __restrict__ T, const int* __restrict__ offs,
                                                  const int* __restrict__ counts, const float* __restrict__ dis,
                                                  const int* __restrict__ srcs, const float* __restrict__ bias,
                                                  u16* __restrict__ Hout) {
    constexpr int TPN = M / 8;
    constexpr int NPB = 256 / TPN;
    int lane = threadIdx.x % TPN;
    int n = blockIdx.x * NPB + threadIdx.x / TPN;
    if (n >= NN) return;
    const u32x4* T4 = reinterpret_cast<const u32x4*>(T);
    float di = dis[n];
    float sn = di * di;
    u32x4 ts = T4[(size_t)n * TPN + lane];
    float acc[8];
    #pragma unroll
    for (int q = 0; q < 4; ++q) {
        acc[2 * q]     = bf2f((u16)(ts[q] & 0xffffu)) * sn + bias[lane * 8 + 2 * q];
        acc[2 * q + 1] = bf2f((u16)(ts[q] >> 16))     * sn + bias[lane * 8 + 2 * q + 1];
    }
    int st = offs[n], cnt = counts[n];
    int j = 0;
    for (; j + 4 <= cnt; j += 4) {
        int e0 = srcs[st + j], e1 = srcs[st + j + 1], e2 = srcs[st + j + 2], e3 = srcs[st + j + 3];
        float w0 = dis[e0] * di, w1 = dis[e1] * di, w2 = dis[e2] * di, w3 = dis[e3] * di;
        u32x4 g0 = T4[(size_t)e0 * TPN + lane];
        u32x4 g1 = T4[(size_t)e1 * TPN + lane];
        u32x4 g2 = T4[(size_t)e2 * TPN + lane];
        u32x4 g3 = T4[(size_t)e3 * TPN + lane];
        #pragma unroll
        for (int q = 0; q < 4; ++q) {
            acc[2 * q]     += bf2f((u16)(g0[q] & 0xffffu)) * w0;
            acc[2 * q + 1] += bf2f((u16)(g0[q] >> 16))     * w0;
            acc[2 * q]     += bf2f((u16)(g1[q] & 0xffffu)) * w1;
            acc[2 * q + 1] += bf2f((u16)(g1[q] >> 16))     * w1;
            acc[2 * q]     += bf2f((u16)(g2[q] & 0xffffu)) * w2;
            acc[2 * q + 1] += bf2f((u16)(g2[q] >> 16))     * w2;
            acc[2 * q]     += bf2f((u16)(g3[q] & 0xffffu)) * w3;
            acc[2 * q + 1] += bf2f((u16)(g3[q] >> 16))     * w3;
        }
    }
    for (; j < cnt; ++j) {
        int e = srcs[st + j];
        float w = dis[e] * di;
        u32x4 g = T4[(size_t)e * TPN + lane];
        #pragma unroll
        for (int q = 0; q < 4; ++q) {
            acc[2 * q]     += bf2f((u16)(g[q] & 0xffffu)) * w;
            acc[2 * q + 1] += bf2f((u16)(g[q] >> 16))     * w;
        }
    }
    u32x4 ov;
    #pragma unroll
    for (int q = 0; q < 4; ++q) {
        float a0 = acc[2 * q], a1 = acc[2 * q + 1];
        if (RELU) { a0 = fmaxf(a0, 0.0f); a1 = fmaxf(a1, 0.0f); }
        ov[q] = (u32)f2bf(a0) | ((u32)f2bf(a1) << 16);
    }
    reinterpret_cast<u32x4*>(Hout)[(size_t)n * TPN + lane] = ov;
}

// ---------------- global add pool per graph; output dtype branched on flag ----------------
__global__ __launch_bounds__(64) void pool_kernel(const u16* __restrict__ H, const int* __restrict__ batch,
                                                  void* __restrict__ out, const int* __restrict__ flag) {
    int g = blockIdx.x;
    int f = threadIdx.x;
    int lo = 0, hi = NN;
    while (lo < hi) { int mid = (lo + hi) >> 1; if (batch[mid] < g) lo = mid + 1; else hi = mid; }
    int lo2 = lo, hi2 = NN;
    while (lo2 < hi2) { int mid = (lo2 + hi2) >> 1; if (batch[mid] < g + 1) lo2 = mid + 1; else hi2 = mid; }
    float acc = 0.0f;
    int n = lo;
    for (; n + 2 <= lo2; n += 2)
        acc += bf2f(H[(size_t)n * 64 + f]) + bf2f(H[(size_t)(n + 1) * 64 + f]);
    if (n < lo2) acc += bf2f(H[(size_t)n * 64 + f]);
    if (flag[0]) reinterpret_cast<u16*>(out)[g * 64 + f] = f2bf(acc);
    else         reinterpret_cast<float*>(out)[g * 64 + f] = acc;
}

extern "C" void kernel_launch(void* const* d_in, const int* in_sizes, int n_in,
                              void* d_out, int out_size, void* d_ws, size_t ws_size,
                              hipStream_t stream) {
    const void* x     = d_in[0];
    const int* ei     = (const int*)d_in[1];
    const int* batch  = (const int*)d_in[2];
    const void* W_emb = d_in[3];
    const void* b_emb = d_in[4];
    const void* W1    = d_in[5];
    const void* b1    = d_in[6];
    const void* W2    = d_in[7];
    const void* b2    = d_in[8];
    const void* W3    = d_in[9];
    const void* b3    = d_in[10];

    char* p = (char*)d_ws;
    auto alloc = [&](size_t bytes) { void* r = p; p += (bytes + 255) & ~(size_t)255; return r; };
    int*   flag   = (int*)alloc(256);
    int*   counts = (int*)alloc(NN * 4);
    int*   cursor = (int*)alloc(NN * 4);
    int*   offs   = (int*)alloc(NN * 4);
    float* dis    = (float*)alloc(NN * 4);
    int*   bsums  = (int*)alloc(256 * 4);
    int*   srcs   = (int*)alloc((size_t)NE * 4);
    u16*   wembT  = (u16*)alloc(128 * 128 * 2);
    u16*   w1T    = (u16*)alloc(128 * 128 * 2);
    u16*   w2T    = (u16*)alloc(128 * 128 * 2);
    u16*   w3T    = (u16*)alloc(64 * 128 * 2);
    float* bembF  = (float*)alloc(128 * 4);
    float* b1F    = (float*)alloc(128 * 4);
    float* b2F    = (float*)alloc(128 * 4);
    float* b3F    = (float*)alloc(64 * 4);
    u16*   hA     = (u16*)alloc((size_t)(NN + 64) * 128 * 2);
    u16*   hB     = (u16*)alloc((size_t)(NN + 64) * 128 * 2);   // holds canonical bf16 x first

    hipMemsetAsync(counts, 0, NN * 4, stream);

    const int SB = (NN + 2047) / 2048;   // 49
    const int NB = (NN + 255) / 256;     // 391
    const int GB = (NN + 63) / 64;       // 1563

    detect_kernel<<<1, 256, 0, stream>>>((const u32*)x, flag);
    mega_prep<<<MEGA_NB, 256, 0, stream>>>(x, flag, hB, W_emb, W1, W2, W3, wembT, w1T, w2T, w3T,
                                           b_emb, b1, b2, b3, bembF, b1F, b2F, b3F, ei, counts);
    scan1_kernel<<<SB, 256, 0, stream>>>(counts, offs, bsums, dis, cursor);
    scan3_kernel<<<NB, 256, 0, stream>>>(offs, bsums);
    scatter_kernel<<<(NE / 4 + 255) / 256, 256, 0, stream>>>(ei, offs, cursor, srcs);

    // emb: A = bf16? x : cvt(x)=hB -> hA
    gemm_mfma<128><<<GB, 256, 0, stream>>>(hB, (const u16*)x, flag, wembT, bembF, hA);
    // layer-1 gemm: hA -> hB
    gemm_mfma<128><<<GB, 256, 0, stream>>>(hA, nullptr, flag, w1T, nullptr, hB);
    // fused agg1(+b1,relu) + gemm2: hB -> hA
    fused_agg_gemm<128><<<GB, 256, 0, stream>>>(hB, offs, counts, dis, srcs, b1F, w2T, hA);
    // fused agg2(+b2,relu) + gemm3: hA -> hB (64-wide out)
    fused_agg_gemm<64><<<GB, 256, 0, stream>>>(hA, offs, counts, dis, srcs, b2F, w3T, hB);
    // agg3 (+b3, no relu): hB -> hA
    agg_kernel<64, false><<<(NN + 31) / 32, 256, 0, stream>>>(hB, offs, counts, dis, srcs, b3F, hA);
    // pool
    pool_kernel<<<NG, 64, 0, stream>>>(hA, batch, d_out, flag);
}